// Round 9
// baseline (193077.429 us; speedup 1.0000x reference)
//
#include <hip/hip_runtime.h>

// ---------------------------------------------------------------------------
// GRU (T=256, B=16, HID=1024, EMB=512, VOCAB=32000) + vocab projection.
//   prep_*  : cast weights/embeddings to bf16, split W into h-part / x-part
//   gemm_bt : Gx = xe @ Wx^T  (SEPARATE pre-kernel — R3-proven; producing Gx
//             inside mega was the R6-R8 correctness bug)
//   mega    : persistent 256-block kernel. 152KB LDS -> 1 block/CU -> all 256
//     CUs hold exactly one block -> exactly 32 blocks per XCD (pigeonhole).
//     GRU = the 32 blocks on XCD 0 (elected via HW_REG_XCC_ID + ticket):
//       - 32 cols/block; Wz,Wr in LDS (128KB); W_cand in VGPRs (64/lane).
//       - h/rh exchange inside XCD-0's L2: tagged words (tag<<16|bf16),
//         sc0 stores + sc0 polls (single L2 copy -> no staleness, ~200cy).
//       - insurance: dual-store (sc0 + sc0sc1) so if placement breaks,
//         consumers escalate to sc1 (MALL) loads after 256 rounds.
//     Pool = other 224 blocks: 500 Wd-convert items (uncached stores), then
//       8000 projection tiles gated on GRU progress flags + conv_done.
//       GRU blocks join the pool after the recurrence.
// ---------------------------------------------------------------------------

using bf16x8 = __attribute__((ext_vector_type(8))) __bf16;
using f32x4  = __attribute__((ext_vector_type(4))) float;

#define GRUB  32
#define TOTB  256
#define NCONV 500                   // Wd convert items (65536 floats each)
#define NTILE 250                   // 32000/128 col tiles
#define NGRP  32                    // 4096/128 row groups (8 timesteps each)
#define NPROJ (NGRP * NTILE)
#define NITEM (NCONV + NPROJ)

__device__ __forceinline__ unsigned short f2bf(float f) {
  unsigned u = __builtin_bit_cast(unsigned, f);
  u += 0x7FFFu + ((u >> 16) & 1u);          // RNE
  return (unsigned short)(u >> 16);
}
__device__ __forceinline__ f32x4 mfma16(bf16x8 a, bf16x8 b, f32x4 c) {
  return __builtin_amdgcn_mfma_f32_16x16x32_bf16(a, b, c, 0, 0, 0);
}
__device__ __forceinline__ bf16x8 bc8(uint4 v) { return __builtin_bit_cast(bf16x8, v); }

__device__ __forceinline__ void ust32(unsigned* p, unsigned v) {
  __hip_atomic_store(p, v, __ATOMIC_RELAXED, __HIP_MEMORY_SCOPE_AGENT);
}
__device__ __forceinline__ void ust64(unsigned long long* p, unsigned long long v) {
  __hip_atomic_store(p, v, __ATOMIC_RELAXED, __HIP_MEMORY_SCOPE_AGENT);
}
__device__ __forceinline__ unsigned uld32(const unsigned* p) {
  return __hip_atomic_load(p, __ATOMIC_RELAXED, __HIP_MEMORY_SCOPE_AGENT);
}

// dual store: sc0 (updates this XCD's L2 -> fast same-XCD path) + sc0 sc1
// (coherence point, safety copy for the escalation path). Idempotent.
__device__ __forceinline__ void st_tag(unsigned* p, unsigned v) {
  asm volatile("global_store_dword %0, %1, off sc0" :: "v"(p), "v"(v) : "memory");
  asm volatile("global_store_dword %0, %1, off sc0 sc1" :: "v"(p), "v"(v) : "memory");
}

// Poll one wave's K-quarter (8 fragments x 8 tagged words). sc0 loads hit the
// local XCD L2 (the single copy producers update). After 256 failed rounds,
// escalate to sc1 (MALL) loads -- liveness if placement ever breaks.
__device__ __forceinline__ void poll_quarter(const unsigned* base, unsigned tgHi,
                                             bf16x8* af) {
  uint4 wa[8], wb[8];
  unsigned ok = 0;
  int rounds = 0;
  do {
    if (rounds < 256) {
#pragma unroll
      for (int kk = 0; kk < 8; ++kk)
        if (!(ok & (1u << kk))) {
          asm volatile("global_load_dwordx4 %0, %1, off sc0"
                       : "=&v"(wa[kk]) : "v"(base + kk * 32));
          asm volatile("global_load_dwordx4 %0, %1, off sc0"
                       : "=&v"(wb[kk]) : "v"(base + kk * 32 + 4));
        }
    } else {
#pragma unroll
      for (int kk = 0; kk < 8; ++kk)
        if (!(ok & (1u << kk))) {
          asm volatile("global_load_dwordx4 %0, %1, off sc0 sc1"
                       : "=&v"(wa[kk]) : "v"(base + kk * 32));
          asm volatile("global_load_dwordx4 %0, %1, off sc0 sc1"
                       : "=&v"(wb[kk]) : "v"(base + kk * 32 + 4));
        }
      __builtin_amdgcn_s_sleep(8);
    }
    asm volatile("s_waitcnt vmcnt(0)" ::: "memory");
    __builtin_amdgcn_sched_barrier(0);
#pragma unroll
    for (int kk = 0; kk < 8; ++kk)
      if (!(ok & (1u << kk))) {
        unsigned m = (wa[kk].x ^ tgHi) | (wa[kk].y ^ tgHi) |
                     (wa[kk].z ^ tgHi) | (wa[kk].w ^ tgHi) |
                     (wb[kk].x ^ tgHi) | (wb[kk].y ^ tgHi) |
                     (wb[kk].z ^ tgHi) | (wb[kk].w ^ tgHi);
        if (__all((int)(m >> 16) == 0)) ok |= 1u << kk;
      }
    ++rounds;
  } while (ok != 0xFFu);
#pragma unroll
  for (int kk = 0; kk < 8; ++kk) {
    uint4 r;
    r.x = __builtin_amdgcn_perm(wa[kk].y, wa[kk].x, 0x05040100);
    r.y = __builtin_amdgcn_perm(wa[kk].w, wa[kk].z, 0x05040100);
    r.z = __builtin_amdgcn_perm(wb[kk].y, wb[kk].x, 0x05040100);
    r.w = __builtin_amdgcn_perm(wb[kk].w, wb[kk].z, 0x05040100);
    af[kk] = __builtin_bit_cast(bf16x8, r);
  }
}

// ---------------- prep kernels ----------------

__global__ void prep_w(const float* __restrict__ Wz, const float* __restrict__ Wr,
                       const float* __restrict__ Wm,
                       unsigned short* __restrict__ Whall,
                       unsigned short* __restrict__ Wxall) {
  int i = blockIdx.x * 256 + threadIdx.x;
  int g   = i / 393216;            // 1024*1536/4
  int rem = i % 393216;
  int j   = rem / 384;             // 1536/4
  int k   = (rem % 384) * 4;
  const float* src = (g == 0) ? Wz : (g == 1) ? Wr : Wm;
  float4 v = *(const float4*)(src + (size_t)j * 1536 + k);
  ushort4 o;
  o.x = f2bf(v.x); o.y = f2bf(v.y); o.z = f2bf(v.z); o.w = f2bf(v.w);
  if (k < 1024)
    *(ushort4*)(Whall + ((size_t)(g * 1024 + j) * 1024 + k)) = o;
  else
    *(ushort4*)(Wxall + ((size_t)(g * 1024 + j) * 512 + (k - 1024))) = o;
}

__global__ void prep_xe(const int* __restrict__ x, const float* __restrict__ emb,
                        unsigned short* __restrict__ xebf) {
  int i  = blockIdx.x * 256 + threadIdx.x;
  int tb = i >> 7, k = (i & 127) * 4;
  int tok = x[tb];
  float4 v = *(const float4*)(emb + (size_t)tok * 512 + k);
  ushort4 o;
  o.x = f2bf(v.x); o.y = f2bf(v.y); o.z = f2bf(v.z); o.w = f2bf(v.w);
  *(ushort4*)(xebf + (size_t)tb * 512 + k) = o;
}

// h0 into tagged slot 0 (tag=1) via MALL; GRU first-touch sc0 reads see it.
__global__ void prep_h(const float* __restrict__ h, unsigned* __restrict__ HT) {
  int i = blockIdx.x * 256 + threadIdx.x;
  ust32(HT + i, (1u << 16) | (unsigned)f2bf(h[i]));
}

// ---------------- GEMM: C[M,N] = A[M,K] x B[N,K]^T (Gx precompute) ---------
__global__ __launch_bounds__(256) void gemm_bt(
    const unsigned short* __restrict__ A, const unsigned short* __restrict__ B,
    float* __restrict__ C, int M, int N, int K, int lda, int ldb, int ldc) {
  __shared__ uint4 As[128 * 5];
  __shared__ uint4 Bs[128 * 5];
  const int tid  = threadIdx.x;
  const int wid  = tid >> 6, lane = tid & 63;
  const int wr   = wid >> 1, wc = wid & 1;
  const int m0   = blockIdx.x * 128, n0 = blockIdx.y * 128;
  const int lr   = lane & 15, lk = lane >> 4;

  f32x4 acc[4][4] = {};
  const int nk = K >> 5;
  for (int kt = 0; kt < nk; ++kt) {
#pragma unroll
    for (int c = 0; c < 2; ++c) {
      int chunk = c * 256 + tid;
      int row = chunk >> 2, kc = chunk & 3;
      As[row * 5 + kc] = *(const uint4*)(A + (size_t)(m0 + row) * lda + kt * 32 + kc * 8);
      Bs[row * 5 + kc] = *(const uint4*)(B + (size_t)(n0 + row) * ldb + kt * 32 + kc * 8);
    }
    __syncthreads();
    bf16x8 af[4], bg[4];
#pragma unroll
    for (int i = 0; i < 4; ++i) {
      af[i] = bc8(As[(wr * 64 + i * 16 + lr) * 5 + lk]);
      bg[i] = bc8(Bs[(wc * 64 + i * 16 + lr) * 5 + lk]);
    }
#pragma unroll
    for (int i = 0; i < 4; ++i)
#pragma unroll
      for (int j = 0; j < 4; ++j)
        acc[i][j] = mfma16(af[i], bg[j], acc[i][j]);
    __syncthreads();
  }
#pragma unroll
  for (int i = 0; i < 4; ++i) {
    int mb = m0 + wr * 64 + i * 16 + lk * 4;
#pragma unroll
    for (int j = 0; j < 4; ++j) {
      int n = n0 + wc * 64 + j * 16 + lr;
#pragma unroll
      for (int q = 0; q < 4; ++q)
        C[(size_t)(mb + q) * ldc + n] = acc[i][j][q];
    }
  }
}

// ---------------- mega kernel ----------------
// flags (uints): [slot*32] per-GRU-block completed steps (32 slots);
// [2048] pool ticket; [2080] conv_done; [2144] gru election ticket.

__global__ __launch_bounds__(256, 1) void mega(
    const unsigned short* __restrict__ Whall, const float* __restrict__ Gx,
    const float* __restrict__ h0f,
    unsigned* __restrict__ HT, unsigned* __restrict__ RT,
    float* __restrict__ outh, unsigned short* __restrict__ allh,
    const float* __restrict__ Wd, unsigned short* __restrict__ Wdbf,
    float* __restrict__ outy, unsigned* __restrict__ flags) {
  __shared__ uint4 smem[9744];                 // 155,904 B -> 1 block/CU
  const int tid = threadIdx.x;
  unsigned* ctrp  = flags + 2048;
  unsigned* convp = flags + 2080;
  unsigned* grutk = flags + 2144;
  int* ish = (int*)(smem + 9728);

  // ---- role election: the 32 blocks on XCD 0 run the GRU ----
  if (tid == 0) {
    unsigned xcd = __builtin_amdgcn_s_getreg((31u << 11) | (0u << 6) | 20u) & 0xFu;
    int s = -1;
    if (xcd == 0u)
      s = (int)__hip_atomic_fetch_add(grutk, 1u, __ATOMIC_RELAXED,
                                      __HIP_MEMORY_SCOPE_AGENT);
    ish[0] = s;
  }
  __syncthreads();
  const int slot = ish[0];
  __syncthreads();

  if (slot >= 0 && slot < GRUB) {
    // ------------- GRU recurrence (32 cols per block) -------------
    uint4* Wl = smem;                          // [2 gates][32 cols][128] swz
    float* redf = (float*)(smem + 8192);       // 3 slots x [4][16][32]
    const int lane = tid & 63, wq = tid >> 6;
    const int c0 = slot * 32;
    const int lr = lane & 15, lk = lane >> 4;
    const int bKu = wq * 32;                   // wave K-quarter (uint4 units)

    for (int it = 0; it < 32; ++it) {
      int chunk = it * 256 + tid;              // 0..8191
      int g = chunk >> 12, rem = chunk & 4095;
      int cl = rem >> 7, k8 = rem & 127;
      uint4 v = *(const uint4*)(Whall + ((size_t)(g * 1024 + c0 + cl) * 1024 + k8 * 8));
      Wl[(g * 32 + cl) * 128 + (k8 ^ (cl & 7))] = v;
    }
    uint4 wcr[16];                             // W_cand fragments in VGPRs
#pragma unroll
    for (int ct = 0; ct < 2; ++ct)
#pragma unroll
      for (int kk = 0; kk < 8; ++kk)
        wcr[ct * 8 + kk] = *(const uint4*)(Whall +
            ((size_t)(2048 + c0 + ct * 16 + lr) * 1024 +
             (size_t)(bKu + kk * 4 + lk) * 8));

    const int bA = tid >> 5, cl_ = tid & 31;   // thread owns rows bA, bA+8
    const int cg = c0 + cl_;
    float hpA = h0f[bA * 1024 + cg];
    float hpB = h0f[(bA + 8) * 1024 + cg];
    unsigned* myflagp = flags + (slot << 5);
    const unsigned lane_off = (unsigned)(lr * 1024 + (bKu + lk) * 8);

    if (tid < 4) ((volatile int*)ish)[tid] = 0;
    __syncthreads();

    float zvA = 0.f, zvB = 0.f;
    for (int t = 0; t < 256; ++t) {
      const unsigned tgHi = (unsigned)(t + 1) << 16;
      // Gx read CACHED (produced by the gemm_bt pre-kernel — R3-proven)
      const size_t rowA = (size_t)(t * 16 + bA) * 3072 + cg;
      float gzA = Gx[rowA], grA = Gx[rowA + 1024], gcA = Gx[rowA + 2048];
      const size_t rowB = rowA + 8 * 3072;
      float gzB = Gx[rowB], grB = Gx[rowB + 1024], gcB = Gx[rowB + 2048];

      // ---- phase 1: z, r (poll tagged h slot t from local L2) ----
      bf16x8 af[8];
      poll_quarter(HT + (size_t)t * 16384 + lane_off, tgHi, af);

      // progress publish (this wave's stores of steps < t are drained by
      // poll_quarter's vmcnt(0); flag = min over the 4 waves)
      if (lane == 0) ((volatile int*)ish)[wq] = t;
      if (tid == 0) {
        volatile int* wd = (volatile int*)ish;
        int mn = min(min(wd[0], wd[1]), min(wd[2], wd[3]));
        if (mn > 0) ust32(myflagp, (unsigned)mn);
      }

      f32x4 az0 = {}, az1 = {}, ar0 = {}, ar1 = {};
#pragma unroll
      for (int kk = 0; kk < 8; ++kk) {
        int sw = (bKu + kk * 4 + lk) ^ (lr & 7);
        bf16x8 a = af[kk];
        az0 = mfma16(a, bc8(Wl[lr * 128 + sw]), az0);
        az1 = mfma16(a, bc8(Wl[(16 + lr) * 128 + sw]), az1);
        ar0 = mfma16(a, bc8(Wl[(32 + lr) * 128 + sw]), ar0);
        ar1 = mfma16(a, bc8(Wl[(48 + lr) * 128 + sw]), ar1);
      }
#pragma unroll
      for (int q = 0; q < 4; ++q) {
        int ro = (lk * 4 + q) * 32;
        redf[wq * 512 + ro + lr]             = az0[q];
        redf[wq * 512 + ro + 16 + lr]        = az1[q];
        redf[2048 + wq * 512 + ro + lr]      = ar0[q];
        redf[2048 + wq * 512 + ro + 16 + lr] = ar1[q];
      }
      __syncthreads();
      {
        int rcA = tid, rcB = tid + 256;        // m*32+col, m=bA / bA+8
        float szA = redf[rcA] + redf[512 + rcA] + redf[1024 + rcA] + redf[1536 + rcA] + gzA;
        float srA = redf[2048 + rcA] + redf[2560 + rcA] + redf[3072 + rcA] + redf[3584 + rcA] + grA;
        float szB = redf[rcB] + redf[512 + rcB] + redf[1024 + rcB] + redf[1536 + rcB] + gzB;
        float srB = redf[2048 + rcB] + redf[2560 + rcB] + redf[3072 + rcB] + redf[3584 + rcB] + grB;
        zvA = 1.f / (1.f + __expf(-szA));
        zvB = 1.f / (1.f + __expf(-szB));
        float rvA = 1.f / (1.f + __expf(-srA));
        float rvB = 1.f / (1.f + __expf(-srB));
        unsigned* rt = RT + (size_t)t * 16384;
        st_tag(rt + bA * 1024 + cg, tgHi | (unsigned)f2bf(rvA * hpA));
        st_tag(rt + (bA + 8) * 1024 + cg, tgHi | (unsigned)f2bf(rvB * hpB));
      }

      // ---- phase 2: cand, h_new (poll tagged rh slot t) ----
      poll_quarter(RT + (size_t)t * 16384 + lane_off, tgHi, af);
      f32x4 ac0 = {}, ac1 = {};
#pragma unroll
      for (int kk = 0; kk < 8; ++kk) {
        ac0 = mfma16(af[kk], bc8(wcr[kk]), ac0);
        ac1 = mfma16(af[kk], bc8(wcr[8 + kk]), ac1);
      }
#pragma unroll
      for (int q = 0; q < 4; ++q) {
        int ro = (lk * 4 + q) * 32;
        redf[4096 + wq * 512 + ro + lr]      = ac0[q];
        redf[4096 + wq * 512 + ro + 16 + lr] = ac1[q];
      }
      __syncthreads();
      {
        int rcA = tid, rcB = tid + 256;
        float scA = redf[4096 + rcA] + redf[4608 + rcA] + redf[5120 + rcA] + redf[5632 + rcA] + gcA;
        float scB = redf[4096 + rcB] + redf[4608 + rcB] + redf[5120 + rcB] + redf[5632 + rcB] + gcB;
        float hnA = (1.f - zvA) * hpA + zvA * tanhf(scA);
        float hnB = (1.f - zvB) * hpB + zvB * tanhf(scB);
        hpA = hnA; hpB = hnB;
        unsigned* ht = HT + (size_t)(t + 1) * 16384;
        unsigned tg2 = (unsigned)(t + 2) << 16;
        unsigned short myA = f2bf(hnA), myB = f2bf(hnB);
        st_tag(ht + bA * 1024 + cg, tg2 | (unsigned)myA);
        st_tag(ht + (bA + 8) * 1024 + cg, tg2 | (unsigned)myB);
        unsigned oA = __shfl_xor((unsigned)myA, 1);
        unsigned oB = __shfl_xor((unsigned)myB, 1);
        if ((cl_ & 1) == 0) {
          ust32((unsigned*)allh + (((size_t)t * 16384 + bA * 1024 + cg) >> 1),
                (unsigned)myA | (oA << 16));
          ust32((unsigned*)allh + (((size_t)t * 16384 + (bA + 8) * 1024 + cg) >> 1),
                (unsigned)myB | (oB << 16));
        }
        outh[(size_t)(t * 16 + bA) * 1024 + cg] = hnA;
        outh[(size_t)(t * 16 + bA + 8) * 1024 + cg] = hnB;
      }
    }
    asm volatile("s_waitcnt vmcnt(0)" ::: "memory");
    __syncthreads();
    if (tid == 0) ust32(myflagp, 256u);
  }

  // ------------- work pool: Wd convert, then projection -------------
  __syncthreads();
  uint4* As = smem;
  uint4* Bs = smem + 640;
  const int wid = tid >> 6, lane = tid & 63;
  const int wr = wid >> 1, wc = wid & 1;
  const int lr = lane & 15, lk = lane >> 4;

  for (;;) {
    __syncthreads();
    if (tid == 0)
      ish[8] = (int)__hip_atomic_fetch_add(ctrp, 1u, __ATOMIC_RELAXED,
                                           __HIP_MEMORY_SCOPE_AGENT);
    __syncthreads();
    unsigned w = (unsigned)ish[8];
    if (w >= (unsigned)NITEM) break;

    if (w < (unsigned)NCONV) {
      const float4* src = (const float4*)Wd + (size_t)w * 16384;
      unsigned long long* dst = (unsigned long long*)Wdbf + (size_t)w * 16384;
      for (int it = 0; it < 64; ++it) {
        int idx = it * 256 + tid;
        float4 v = src[idx];
        ushort4 o;
        o.x = f2bf(v.x); o.y = f2bf(v.y); o.z = f2bf(v.z); o.w = f2bf(v.w);
        ust64(dst + idx, __builtin_bit_cast(unsigned long long, o));
      }
      asm volatile("s_waitcnt vmcnt(0)" ::: "memory");
      __syncthreads();
      if (tid == 0)
        __hip_atomic_fetch_add(convp, 1u, __ATOMIC_RELAXED, __HIP_MEMORY_SCOPE_AGENT);
      continue;
    }

    unsigned p = w - NCONV;
    int g = (int)(p / NTILE), nt = (int)(p % NTILE);
    int m0 = g * 128, n0 = nt * 128;

    // gate: all 32 GRU slots past step 8g+8 (rows [m0,m0+128) drained)
    unsigned tgt = 8u * (unsigned)g + 8u;
    if (tid < GRUB) {
      const unsigned* f = flags + tid * 32;
      while (uld32(f) < tgt) __builtin_amdgcn_s_sleep(8);
    }
    if (tid == 0)
      while (uld32(convp) < (unsigned)NCONV) __builtin_amdgcn_s_sleep(8);
    __syncthreads();

    f32x4 acc[4][4] = {};
    for (int kt = 0; kt < 32; ++kt) {
#pragma unroll
      for (int c = 0; c < 2; ++c) {
        int chunk = c * 256 + tid;
        int row = chunk >> 2, kc = chunk & 3;
        As[row * 5 + kc] = *(const uint4*)(allh + (size_t)(m0 + row) * 1024 + kt * 32 + kc * 8);
        Bs[row * 5 + kc] = *(const uint4*)(Wdbf + (size_t)(n0 + row) * 1024 + kt * 32 + kc * 8);
      }
      __syncthreads();
      bf16x8 afr[4], bg[4];
#pragma unroll
      for (int i = 0; i < 4; ++i) {
        afr[i] = bc8(As[(wr * 64 + i * 16 + lr) * 5 + lk]);
        bg[i]  = bc8(Bs[(wc * 64 + i * 16 + lr) * 5 + lk]);
      }
#pragma unroll
      for (int i = 0; i < 4; ++i)
#pragma unroll
        for (int j = 0; j < 4; ++j)
          acc[i][j] = mfma16(afr[i], bg[j], acc[i][j]);
      __syncthreads();
    }
#pragma unroll
    for (int i = 0; i < 4; ++i) {
      int mb = m0 + wr * 64 + i * 16 + lk * 4;
#pragma unroll
      for (int j = 0; j < 4; ++j) {
        int n = n0 + wc * 64 + j * 16 + lr;
#pragma unroll
        for (int q = 0; q < 4; ++q)
          outy[(size_t)(mb + q) * 32000 + n] = acc[i][j][q];
      }
    }
  }
}

// ---------------- workspace layout (bytes) ----------------
constexpr size_t OFF_WH  = 0;                                  // 6.3 MB
constexpr size_t OFF_WX  = OFF_WH + 3ull * 1024 * 1024 * 2;    // 3.1 MB
constexpr size_t OFF_WD  = OFF_WX + 3ull * 1024 * 512 * 2;     // 65.5 MB
constexpr size_t OFF_XE  = OFF_WD + 32000ull * 1024 * 2;       // 4.2 MB
constexpr size_t OFF_GX  = OFF_XE + 4096ull * 512 * 2;         // 50.3 MB
constexpr size_t OFF_AH  = OFF_GX + 4096ull * 3072 * 4;        // 8.4 MB
constexpr size_t OFF_HT  = OFF_AH + 4096ull * 1024 * 2;        // 16.9 MB tagged h
constexpr size_t OFF_RT  = OFF_HT + 257ull * 16384 * 4;        // 16.8 MB tagged rh
constexpr size_t OFF_FLG = OFF_RT + 256ull * 16384 * 4;        // 16 KB
constexpr size_t ZERO_SZ = OFF_FLG - OFF_HT;                   // HT+RT

extern "C" void kernel_launch(void* const* d_in, const int* in_sizes, int n_in,
                              void* d_out, int out_size, void* d_ws, size_t ws_size,
                              hipStream_t stream) {
  const int*   x   = (const int*)d_in[0];
  const float* h0  = (const float*)d_in[1];
  const float* emb = (const float*)d_in[2];
  const float* Wz  = (const float*)d_in[3];
  const float* Wr  = (const float*)d_in[4];
  const float* Wm  = (const float*)d_in[5];
  const float* Wd  = (const float*)d_in[6];

  float* out_h = (float*)d_out;                        // [256*16, 1024]
  float* out_y = out_h + 4096ull * 1024;               // [256*16, 32000]

  char* ws = (char*)d_ws;
  unsigned short* Whall = (unsigned short*)(ws + OFF_WH);
  unsigned short* Wxall = (unsigned short*)(ws + OFF_WX);
  unsigned short* Wdbf  = (unsigned short*)(ws + OFF_WD);
  unsigned short* xebf  = (unsigned short*)(ws + OFF_XE);
  float*          Gx    = (float*)(ws + OFF_GX);
  unsigned short* allh  = (unsigned short*)(ws + OFF_AH);
  unsigned*       HT    = (unsigned*)(ws + OFF_HT);
  unsigned*       RT    = (unsigned*)(ws + OFF_RT);
  unsigned*       flags = (unsigned*)(ws + OFF_FLG);

  // zero tags + flags every call (graph replays rerun this)
  hipMemsetAsync(ws + OFF_HT, 0, ZERO_SZ, stream);
  hipMemsetAsync(flags, 0, 16384, stream);

  prep_w <<<4608, 256, 0, stream>>>(Wz, Wr, Wm, Whall, Wxall);
  prep_xe<<<2048, 256, 0, stream>>>(x, emb, xebf);
  prep_h <<<64, 256, 0, stream>>>(h0, HT);

  // Gx[tb][g*1024+c] = xe[tb] . Wx_g[c]   (M=4096, N=3072, K=512)
  gemm_bt<<<dim3(32, 24), 256, 0, stream>>>(xebf, Wxall, Gx,
                                            4096, 3072, 512, 512, 512, 3072);

  mega<<<TOTB, 256, 0, stream>>>(Whall, Gx, h0, HT, RT,
                                 out_h, allh, Wd, Wdbf, out_y, flags);
}

// Round 10
// 1665.991 us; speedup vs baseline: 115.8934x; 115.8934x over previous
//
#include <hip/hip_runtime.h>

// ---------------------------------------------------------------------------
// GRU (T=256, B=16, HID=1024, EMB=512, VOCAB=32000) + vocab projection.
// All components individually proven in prior rounds:
//   prep_*  : cast weights/embeddings to bf16 (R1+)
//   gemm_bt : Gx = xe @ Wx^T, separate pre-kernel (R3/R9; in-mega Gx corrupts)
//   mega    : persistent 256-block kernel (152KB LDS -> 1 block/CU).
//     blocks 0..31  : GRU recurrence, 32 cols/block (math validated R9):
//       Wz,Wr in LDS (128KB, XOR-swizzled), W_cand in VGPRs (64/lane),
//       h fp32 in registers; exchange via MALL (uncached packed stores,
//       flag_bar grid barrier, cached first-touch slot reads — R3-proven).
//     blocks 32..255: pool: 500 Wd-convert items (uncached stores, R5/R9-
//       proven), then 8000 projection tiles gated on stepp+convp (R3-proven).
//       GRU blocks join the pool after the recurrence.
// ---------------------------------------------------------------------------

using bf16x8 = __attribute__((ext_vector_type(8))) __bf16;
using f32x4  = __attribute__((ext_vector_type(4))) float;

#define GRUB  32
#define TOTB  256
#define NCONV 500                   // Wd convert items (65536 floats each)
#define NTILE 250                   // 32000/128 col tiles
#define NGRP  32                    // 4096/128 row groups (8 timesteps each)
#define NITEM (NCONV + NGRP * NTILE)

__device__ __forceinline__ unsigned short f2bf(float f) {
  unsigned u = __builtin_bit_cast(unsigned, f);
  u += 0x7FFFu + ((u >> 16) & 1u);          // RNE
  return (unsigned short)(u >> 16);
}
__device__ __forceinline__ f32x4 mfma16(bf16x8 a, bf16x8 b, f32x4 c) {
  return __builtin_amdgcn_mfma_f32_16x16x32_bf16(a, b, c, 0, 0, 0);
}
__device__ __forceinline__ bf16x8 bc8(uint4 v) { return __builtin_bit_cast(bf16x8, v); }

__device__ __forceinline__ void ust32(unsigned* p, unsigned v) {
  __hip_atomic_store(p, v, __ATOMIC_RELAXED, __HIP_MEMORY_SCOPE_AGENT);
}
__device__ __forceinline__ void ust64(unsigned long long* p, unsigned long long v) {
  __hip_atomic_store(p, v, __ATOMIC_RELAXED, __HIP_MEMORY_SCOPE_AGENT);
}
__device__ __forceinline__ unsigned uld32(const unsigned* p) {
  return __hip_atomic_load(p, __ATOMIC_RELAXED, __HIP_MEMORY_SCOPE_AGENT);
}

// ---------------- prep kernels ----------------

__global__ void prep_w(const float* __restrict__ Wz, const float* __restrict__ Wr,
                       const float* __restrict__ Wm,
                       unsigned short* __restrict__ Whall,
                       unsigned short* __restrict__ Wxall) {
  int i = blockIdx.x * 256 + threadIdx.x;
  int g   = i / 393216;            // 1024*1536/4
  int rem = i % 393216;
  int j   = rem / 384;             // 1536/4
  int k   = (rem % 384) * 4;
  const float* src = (g == 0) ? Wz : (g == 1) ? Wr : Wm;
  float4 v = *(const float4*)(src + (size_t)j * 1536 + k);
  ushort4 o;
  o.x = f2bf(v.x); o.y = f2bf(v.y); o.z = f2bf(v.z); o.w = f2bf(v.w);
  if (k < 1024)
    *(ushort4*)(Whall + ((size_t)(g * 1024 + j) * 1024 + k)) = o;
  else
    *(ushort4*)(Wxall + ((size_t)(g * 1024 + j) * 512 + (k - 1024))) = o;
}

__global__ void prep_xe(const int* __restrict__ x, const float* __restrict__ emb,
                        unsigned short* __restrict__ xebf) {
  int i  = blockIdx.x * 256 + threadIdx.x;
  int tb = i >> 7, k = (i & 127) * 4;
  int tok = x[tb];
  float4 v = *(const float4*)(emb + (size_t)tok * 512 + k);
  ushort4 o;
  o.x = f2bf(v.x); o.y = f2bf(v.y); o.z = f2bf(v.z); o.w = f2bf(v.w);
  *(ushort4*)(xebf + (size_t)tb * 512 + k) = o;
}

__global__ void prep_h(const float* __restrict__ h, unsigned short* __restrict__ hbf) {
  int i = blockIdx.x * 256 + threadIdx.x;
  hbf[i] = f2bf(h[i]);
}

// ---------------- GEMM: C[M,N] = A[M,K] x B[N,K]^T (Gx precompute) ---------
__global__ __launch_bounds__(256) void gemm_bt(
    const unsigned short* __restrict__ A, const unsigned short* __restrict__ B,
    float* __restrict__ C, int M, int N, int K, int lda, int ldb, int ldc) {
  __shared__ uint4 As[128 * 5];
  __shared__ uint4 Bs[128 * 5];
  const int tid  = threadIdx.x;
  const int wid  = tid >> 6, lane = tid & 63;
  const int wr   = wid >> 1, wc = wid & 1;
  const int m0   = blockIdx.x * 128, n0 = blockIdx.y * 128;
  const int lr   = lane & 15, lk = lane >> 4;

  f32x4 acc[4][4] = {};
  const int nk = K >> 5;
  for (int kt = 0; kt < nk; ++kt) {
#pragma unroll
    for (int c = 0; c < 2; ++c) {
      int chunk = c * 256 + tid;
      int row = chunk >> 2, kc = chunk & 3;
      As[row * 5 + kc] = *(const uint4*)(A + (size_t)(m0 + row) * lda + kt * 32 + kc * 8);
      Bs[row * 5 + kc] = *(const uint4*)(B + (size_t)(n0 + row) * ldb + kt * 32 + kc * 8);
    }
    __syncthreads();
    bf16x8 af[4], bg[4];
#pragma unroll
    for (int i = 0; i < 4; ++i) {
      af[i] = bc8(As[(wr * 64 + i * 16 + lr) * 5 + lk]);
      bg[i] = bc8(Bs[(wc * 64 + i * 16 + lr) * 5 + lk]);
    }
#pragma unroll
    for (int i = 0; i < 4; ++i)
#pragma unroll
      for (int j = 0; j < 4; ++j)
        acc[i][j] = mfma16(af[i], bg[j], acc[i][j]);
    __syncthreads();
  }
#pragma unroll
  for (int i = 0; i < 4; ++i) {
    int mb = m0 + wr * 64 + i * 16 + lk * 4;
#pragma unroll
    for (int j = 0; j < 4; ++j) {
      int n = n0 + wc * 64 + j * 16 + lr;
#pragma unroll
      for (int q = 0; q < 4; ++q)
        C[(size_t)(mb + q) * ldc + n] = acc[i][j][q];
    }
  }
}

// ---------------- mega kernel ----------------
// flags (uints): [bid*32] barrier flags (32 GRU blocks); [2048] gru_step;
// [2080] pool ticket; [2112] conv_done.

__device__ __forceinline__ void flag_bar(unsigned* flags, unsigned seq) {
  __syncthreads();               // drains vmcnt -> data stores at coherence pt
  if (threadIdx.x < GRUB) {
    if (threadIdx.x == 0)
      ust32(&flags[blockIdx.x * 32], seq);
    unsigned* f = &flags[threadIdx.x * 32];
    while (uld32(f) < seq) {}
  }
  __syncthreads();
}

__global__ __launch_bounds__(256, 1) void mega(
    const unsigned short* __restrict__ Whall, const float* __restrict__ Gx,
    const unsigned short* __restrict__ h0bf, const float* __restrict__ h0f,
    unsigned short* __restrict__ rhs, float* __restrict__ outh,
    unsigned short* __restrict__ allh,
    const float* __restrict__ Wd, unsigned short* __restrict__ Wdbf,
    float* __restrict__ outy, unsigned* __restrict__ flags) {
  __shared__ uint4 smem[9744];                 // 155,904 B -> 1 block/CU
  const int tid = threadIdx.x;
  const int bid = blockIdx.x;
  unsigned* stepp = flags + 2048;
  unsigned* ctrp  = flags + 2080;
  unsigned* convp = flags + 2112;
  unsigned* wsh   = (unsigned*)(smem + 9728);

  if (bid < GRUB) {
    // ------------- GRU recurrence (32 cols/block; math validated R9) ------
    uint4* Wl = smem;                          // [2 gates][32 cols][128] swz
    float* redf = (float*)(smem + 8192);       // 3 slots x [4][16][32] floats
    const int lane = tid & 63, wq = tid >> 6;
    const int c0 = bid * 32;
    const int lr = lane & 15, lk = lane >> 4;
    const int bKu = wq * 32;                   // wave K-quarter (uint4 units)

    for (int it = 0; it < 32; ++it) {
      int chunk = it * 256 + tid;              // 0..8191
      int g = chunk >> 12, rem = chunk & 4095;
      int cl = rem >> 7, k8 = rem & 127;
      uint4 v = *(const uint4*)(Whall + ((size_t)(g * 1024 + c0 + cl) * 1024 + k8 * 8));
      Wl[(g * 32 + cl) * 128 + (k8 ^ (cl & 7))] = v;
    }
    uint4 wcr[16];                             // W_cand fragments in VGPRs
#pragma unroll
    for (int ct = 0; ct < 2; ++ct)
#pragma unroll
      for (int kk = 0; kk < 8; ++kk)
        wcr[ct * 8 + kk] = *(const uint4*)(Whall +
            ((size_t)(2048 + c0 + ct * 16 + lr) * 1024 +
             (size_t)(bKu + kk * 4 + lk) * 8));

    const int bA = tid >> 5, cl_ = tid & 31;   // thread owns rows bA, bA+8
    const int cg = c0 + cl_;
    float hpA = h0f[bA * 1024 + cg];
    float hpB = h0f[(bA + 8) * 1024 + cg];
    __syncthreads();

    float zvA = 0.f, zvB = 0.f;
    for (int t = 0; t < 256; ++t) {
      // Gx prefetch (cached; produced by gemm_bt pre-kernel)
      const size_t rowA = (size_t)(t * 16 + bA) * 3072 + cg;
      float gzA = Gx[rowA], grA = Gx[rowA + 1024], gcA = Gx[rowA + 2048];
      const size_t rowB = rowA + 8 * 3072;
      float gzB = Gx[rowB], grB = Gx[rowB + 1024], gcB = Gx[rowB + 2048];

      // ---- phase 1: z, r (h_prev read CACHED from write-once slot) ----
      const uint4* hp4 = (t == 0) ? (const uint4*)h0bf
                                  : (const uint4*)(allh + (size_t)(t - 1) * 16384);
      f32x4 az0 = {}, az1 = {}, ar0 = {}, ar1 = {};
#pragma unroll
      for (int kk = 0; kk < 8; ++kk) {
        int ku = bKu + kk * 4 + lk;            // 0..127
        bf16x8 a = bc8(hp4[lr * 128 + ku]);
        int sw = ku ^ (lr & 7);
        az0 = mfma16(a, bc8(Wl[lr * 128 + sw]), az0);
        az1 = mfma16(a, bc8(Wl[(16 + lr) * 128 + sw]), az1);
        ar0 = mfma16(a, bc8(Wl[(32 + lr) * 128 + sw]), ar0);
        ar1 = mfma16(a, bc8(Wl[(48 + lr) * 128 + sw]), ar1);
      }
#pragma unroll
      for (int q = 0; q < 4; ++q) {
        int ro = (lk * 4 + q) * 32;
        redf[wq * 512 + ro + lr]             = az0[q];
        redf[wq * 512 + ro + 16 + lr]        = az1[q];
        redf[2048 + wq * 512 + ro + lr]      = ar0[q];
        redf[2048 + wq * 512 + ro + 16 + lr] = ar1[q];
      }
      __syncthreads();
      {
        int rcA = tid, rcB = tid + 256;        // m*32+col, m=bA / bA+8
        float szA = redf[rcA] + redf[512 + rcA] + redf[1024 + rcA] + redf[1536 + rcA] + gzA;
        float srA = redf[2048 + rcA] + redf[2560 + rcA] + redf[3072 + rcA] + redf[3584 + rcA] + grA;
        float szB = redf[rcB] + redf[512 + rcB] + redf[1024 + rcB] + redf[1536 + rcB] + gzB;
        float srB = redf[2048 + rcB] + redf[2560 + rcB] + redf[3072 + rcB] + redf[3584 + rcB] + grB;
        zvA = 1.f / (1.f + __expf(-szA));
        zvB = 1.f / (1.f + __expf(-szB));
        float rvA = 1.f / (1.f + __expf(-srA));
        float rvB = 1.f / (1.f + __expf(-srB));
        unsigned short mA = f2bf(rvA * hpA), mB = f2bf(rvB * hpB);
        unsigned oA = __shfl_xor((unsigned)mA, 1);
        unsigned oB = __shfl_xor((unsigned)mB, 1);
        if ((cl_ & 1) == 0) {
          ust32((unsigned*)rhs + (((size_t)t * 16384 + bA * 1024 + cg) >> 1),
                (unsigned)mA | (oA << 16));
          ust32((unsigned*)rhs + (((size_t)t * 16384 + (bA + 8) * 1024 + cg) >> 1),
                (unsigned)mB | (oB << 16));
        }
      }
      flag_bar(flags, 2u * (unsigned)t + 1u);

      // ---- phase 2: cand, h_new (rh read CACHED from write-once slot) ----
      const uint4* rt4 = (const uint4*)(rhs + (size_t)t * 16384);
      f32x4 ac0 = {}, ac1 = {};
#pragma unroll
      for (int kk = 0; kk < 8; ++kk) {
        int ku = bKu + kk * 4 + lk;
        bf16x8 a = bc8(rt4[lr * 128 + ku]);
        ac0 = mfma16(a, bc8(wcr[kk]), ac0);
        ac1 = mfma16(a, bc8(wcr[8 + kk]), ac1);
      }
#pragma unroll
      for (int q = 0; q < 4; ++q) {
        int ro = (lk * 4 + q) * 32;
        redf[4096 + wq * 512 + ro + lr]      = ac0[q];
        redf[4096 + wq * 512 + ro + 16 + lr] = ac1[q];
      }
      __syncthreads();
      {
        int rcA = tid, rcB = tid + 256;
        float scA = redf[4096 + rcA] + redf[4608 + rcA] + redf[5120 + rcA] + redf[5632 + rcA] + gcA;
        float scB = redf[4096 + rcB] + redf[4608 + rcB] + redf[5120 + rcB] + redf[5632 + rcB] + gcB;
        float hnA = (1.f - zvA) * hpA + zvA * tanhf(scA);
        float hnB = (1.f - zvB) * hpB + zvB * tanhf(scB);
        hpA = hnA; hpB = hnB;
        unsigned short mA = f2bf(hnA), mB = f2bf(hnB);
        unsigned oA = __shfl_xor((unsigned)mA, 1);
        unsigned oB = __shfl_xor((unsigned)mB, 1);
        if ((cl_ & 1) == 0) {
          ust32((unsigned*)allh + (((size_t)t * 16384 + bA * 1024 + cg) >> 1),
                (unsigned)mA | (oA << 16));
          ust32((unsigned*)allh + (((size_t)t * 16384 + (bA + 8) * 1024 + cg) >> 1),
                (unsigned)mB | (oB << 16));
        }
        outh[(size_t)(t * 16 + bA) * 1024 + cg] = hnA;
        outh[(size_t)(t * 16 + bA + 8) * 1024 + cg] = hnB;
      }
      flag_bar(flags, 2u * (unsigned)t + 2u);
      if (bid == 0 && tid == 0) ust32(stepp, (unsigned)t + 1u);
    }
  }

  // ------------- work pool: Wd convert, then projection -------------
  __syncthreads();
  uint4* As = smem;
  uint4* Bs = smem + 640;
  const int wid = tid >> 6, lane = tid & 63;
  const int wr = wid >> 1, wc = wid & 1;
  const int lr = lane & 15, lk = lane >> 4;

  for (;;) {
    __syncthreads();
    if (tid == 0) {
      unsigned w = __hip_atomic_fetch_add(ctrp, 1u, __ATOMIC_RELAXED,
                                          __HIP_MEMORY_SCOPE_AGENT);
      if (w >= (unsigned)NCONV && w < (unsigned)NITEM) {
        unsigned p = w - NCONV;
        unsigned need = (p / NTILE) * 8u + 8u;         // steps done for group
        while (uld32(stepp) < need) __builtin_amdgcn_s_sleep(32);
        while (uld32(convp) < (unsigned)NCONV) __builtin_amdgcn_s_sleep(8);
      }
      *wsh = w;
    }
    __syncthreads();
    unsigned w = *wsh;
    if (w >= (unsigned)NITEM) break;

    if (w < (unsigned)NCONV) {
      // convert 65536 floats of Wd -> Wdbf, UNCACHED 8B stores (R5/R9-proven)
      const float4* src = (const float4*)Wd + (size_t)w * 16384;
      unsigned long long* dst = (unsigned long long*)Wdbf + (size_t)w * 16384;
      for (int it = 0; it < 64; ++it) {
        int idx = it * 256 + tid;
        float4 v = src[idx];
        ushort4 o;
        o.x = f2bf(v.x); o.y = f2bf(v.y); o.z = f2bf(v.z); o.w = f2bf(v.w);
        ust64(dst + idx, __builtin_bit_cast(unsigned long long, o));
      }
      asm volatile("s_waitcnt vmcnt(0)" ::: "memory");
      __syncthreads();
      if (tid == 0)
        __hip_atomic_fetch_add(convp, 1u, __ATOMIC_RELAXED, __HIP_MEMORY_SCOPE_AGENT);
      continue;
    }

    unsigned p = w - NCONV;
    int g = (int)(p / NTILE), nt = (int)(p % NTILE);
    int m0 = g * 128, n0 = nt * 128;

    f32x4 acc[4][4] = {};
    for (int kt = 0; kt < 32; ++kt) {
#pragma unroll
      for (int c = 0; c < 2; ++c) {
        int chunk = c * 256 + tid;
        int row = chunk >> 2, kc = chunk & 3;
        As[row * 5 + kc] = *(const uint4*)(allh + (size_t)(m0 + row) * 1024 + kt * 32 + kc * 8);
        Bs[row * 5 + kc] = *(const uint4*)(Wdbf + (size_t)(n0 + row) * 1024 + kt * 32 + kc * 8);
      }
      __syncthreads();
      bf16x8 afr[4], bg[4];
#pragma unroll
      for (int i = 0; i < 4; ++i) {
        afr[i] = bc8(As[(wr * 64 + i * 16 + lr) * 5 + lk]);
        bg[i]  = bc8(Bs[(wc * 64 + i * 16 + lr) * 5 + lk]);
      }
#pragma unroll
      for (int i = 0; i < 4; ++i)
#pragma unroll
        for (int j = 0; j < 4; ++j)
          acc[i][j] = mfma16(afr[i], bg[j], acc[i][j]);
      __syncthreads();
    }
#pragma unroll
    for (int i = 0; i < 4; ++i) {
      int mb = m0 + wr * 64 + i * 16 + lk * 4;
#pragma unroll
      for (int j = 0; j < 4; ++j) {
        int n = n0 + wc * 64 + j * 16 + lr;
#pragma unroll
        for (int q = 0; q < 4; ++q)
          outy[(size_t)(mb + q) * 32000 + n] = acc[i][j][q];
      }
    }
  }
}

// ---------------- workspace layout (bytes) ----------------
constexpr size_t OFF_WH  = 0;                                  // 6.3 MB
constexpr size_t OFF_WX  = OFF_WH + 3ull * 1024 * 1024 * 2;    // 3.1 MB
constexpr size_t OFF_WD  = OFF_WX + 3ull * 1024 * 512 * 2;     // 65.5 MB
constexpr size_t OFF_XE  = OFF_WD + 32000ull * 1024 * 2;       // 4.2 MB
constexpr size_t OFF_GX  = OFF_XE + 4096ull * 512 * 2;         // 50.3 MB
constexpr size_t OFF_AH  = OFF_GX + 4096ull * 3072 * 4;        // 8.4 MB
constexpr size_t OFF_H0  = OFF_AH + 4096ull * 1024 * 2;        // 32 KB
constexpr size_t OFF_RHS = OFF_H0 + 16384ull * 2;              // 8.4 MB
constexpr size_t OFF_FLG = OFF_RHS + 256ull * 16384 * 2;       // 16 KB

extern "C" void kernel_launch(void* const* d_in, const int* in_sizes, int n_in,
                              void* d_out, int out_size, void* d_ws, size_t ws_size,
                              hipStream_t stream) {
  const int*   x   = (const int*)d_in[0];
  const float* h0  = (const float*)d_in[1];
  const float* emb = (const float*)d_in[2];
  const float* Wz  = (const float*)d_in[3];
  const float* Wr  = (const float*)d_in[4];
  const float* Wm  = (const float*)d_in[5];
  const float* Wd  = (const float*)d_in[6];

  float* out_h = (float*)d_out;                        // [256*16, 1024]
  float* out_y = out_h + 4096ull * 1024;               // [256*16, 32000]

  char* ws = (char*)d_ws;
  unsigned short* Whall = (unsigned short*)(ws + OFF_WH);
  unsigned short* Wxall = (unsigned short*)(ws + OFF_WX);
  unsigned short* Wdbf  = (unsigned short*)(ws + OFF_WD);
  unsigned short* xebf  = (unsigned short*)(ws + OFF_XE);
  float*          Gx    = (float*)(ws + OFF_GX);
  unsigned short* allh  = (unsigned short*)(ws + OFF_AH);
  unsigned short* h0bf  = (unsigned short*)(ws + OFF_H0);
  unsigned short* rhs   = (unsigned short*)(ws + OFF_RHS);
  unsigned*       flags = (unsigned*)(ws + OFF_FLG);

  hipMemsetAsync(flags, 0, 16384, stream);

  prep_w <<<4608, 256, 0, stream>>>(Wz, Wr, Wm, Whall, Wxall);
  prep_xe<<<2048, 256, 0, stream>>>(x, emb, xebf);
  prep_h <<<64, 256, 0, stream>>>(h0, h0bf);

  // Gx[tb][g*1024+c] = xe[tb] . Wx_g[c]   (M=4096, N=3072, K=512)
  gemm_bt<<<dim3(32, 24), 256, 0, stream>>>(xebf, Wxall, Gx,
                                            4096, 3072, 512, 512, 512, 3072);

  mega<<<TOTB, 256, 0, stream>>>(Whall, Gx, h0bf, h0, rhs,
                                 out_h, allh, Wd, Wdbf, out_y, flags);
}